// Round 7
// baseline (277.260 us; speedup 1.0000x reference)
//
#include <hip/hip_runtime.h>

typedef __bf16 bf16;
typedef __bf16 bf16x8 __attribute__((ext_vector_type(8)));
typedef __bf16 bf16x4 __attribute__((ext_vector_type(4)));
typedef float f32x4 __attribute__((ext_vector_type(4)));

#define MFMA(a, b, c) __builtin_amdgcn_mfma_f32_16x16x32_bf16((a), (b), (c), 0, 0, 0)

static __device__ __forceinline__ f32x4 zero4() {
    f32x4 z; z[0] = 0.f; z[1] = 0.f; z[2] = 0.f; z[3] = 0.f; return z;
}

// LDS-only barrier: all cross-wave deps at these barriers are LDS-carried;
// leaves global loads/stores in flight, unlike __syncthreads().
static __device__ __forceinline__ void soft_barrier() {
    __builtin_amdgcn_sched_barrier(0);
    asm volatile("s_waitcnt lgkmcnt(0)" ::: "memory");
    __builtin_amdgcn_s_barrier();
    __builtin_amdgcn_sched_barrier(0);
}

// ---------------- prep: W (bf16) + W3 (bf16, padded) conversions ----------------
__global__ __launch_bounds__(256) void k_prep(
    const float* __restrict__ Wx, const float* __restrict__ Wy, const float* __restrict__ Wz,
    const float* __restrict__ W3,
    bf16* __restrict__ wbf, bf16* __restrict__ w3b, float* __restrict__ w3bias)
{
    const int b = blockIdx.x, t = threadIdx.x;
    if (b < 96) {
        int proj = b >> 5;
        const float* src = (proj == 0) ? Wx : (proj == 1) ? Wy : Wz;
        bf16* dst = wbf + proj * 131072;
        int o = (b & 31) * 4096 + t * 16;
#pragma unroll
        for (int u = 0; u < 4; u++) {
            float4 v = *(const float4*)(src + o + u * 4);
            bf16x4 w; w[0] = (bf16)v.x; w[1] = (bf16)v.y; w[2] = (bf16)v.z; w[3] = (bf16)v.w;
            *(bf16x4*)(dst + o + u * 4) = w;
        }
    } else {
        int nb = b - 96;                     // 0..2063
        int n = nb * 8 + (t >> 5);           // row of W3 (i*128+k), < 16512
        int c = t & 31;
        const float* row = W3 + n * 129;
        float v0 = row[4 * c + 0];
        float v1 = row[4 * c + 1];
        float v2 = row[4 * c + 2];
        float v3 = row[4 * c + 3];
        bf16x4 w;
        w[0] = (bf16)v0; w[1] = (bf16)v1; w[2] = (bf16)v2; w[3] = (bf16)v3;
        *(bf16x4*)(w3b + n * 136 + 4 * c) = w;
        if (c == 0) w3bias[n] = row[128];
    }
}

// ---------------- MLP: pout[proj][m][p] = leaky_relu(A @ W^T + b) ----------------
__global__ __launch_bounds__(256) void k_mlp(
    const float* __restrict__ xsp, const float* __restrict__ x,
    const bf16* __restrict__ wbf,
    const float* __restrict__ bx, const float* __restrict__ by, const float* __restrict__ bz,
    bf16* __restrict__ pout)
{
    __shared__ bf16 Al[16 * 1032];
    const int proj = blockIdx.y;
    const float* A = (proj == 2) ? x : xsp;
    const bf16* W = wbf + proj * 131072;
    const float* bias = (proj == 0) ? bx : (proj == 1) ? by : bz;
    bf16* out = pout + proj * 262144;

    const int tid = threadIdx.x;
    const int wv = tid >> 6, lane = tid & 63, quad = lane >> 4, lr = lane & 15;
    const int m0 = blockIdx.x * 16;

    {
        const float* Asrc = A + m0 * 1024;
        const int rr = tid >> 7, cc = (tid & 127) * 8;
#pragma unroll
        for (int i = 0; i < 8; i++) {
            int r = i * 2 + rr;
            float4 v0 = *(const float4*)(Asrc + r * 1024 + cc);
            float4 v1 = *(const float4*)(Asrc + r * 1024 + cc + 4);
            bf16x8 w;
            w[0] = (bf16)v0.x; w[1] = (bf16)v0.y; w[2] = (bf16)v0.z; w[3] = (bf16)v0.w;
            w[4] = (bf16)v1.x; w[5] = (bf16)v1.y; w[6] = (bf16)v1.z; w[7] = (bf16)v1.w;
            *(bf16x8*)(&Al[r * 1032 + cc]) = w;
        }
    }
    __syncthreads();

    f32x4 acc[2];
    acc[0] = zero4(); acc[1] = zero4();

    const bf16* brow = Al + lr * 1032 + quad * 8;
    const bf16* arow = W + (wv * 16 + lr) * 1024 + quad * 8;

#pragma unroll 4
    for (int kw = 0; kw < 32; kw++) {
        bf16x8 bfr = *(const bf16x8*)(brow + kw * 32);
        bf16x8 a0 = *(const bf16x8*)(arow + kw * 32);
        bf16x8 a1 = *(const bf16x8*)(arow + 65536 + kw * 32);
        acc[0] = MFMA(a0, bfr, acc[0]);
        acc[1] = MFMA(a1, bfr, acc[1]);
    }
#pragma unroll
    for (int s = 0; s < 2; s++) {
        int p = (wv + s * 4) * 16 + quad * 4;
        float4 bv = *(const float4*)(bias + p);
        int m = m0 + lr;
        bf16x4 o;
        float v0 = acc[s][0] + bv.x; o[0] = (bf16)(v0 > 0.f ? v0 : 0.1f * v0);
        float v1 = acc[s][1] + bv.y; o[1] = (bf16)(v1 > 0.f ? v1 : 0.1f * v1);
        float v2 = acc[s][2] + bv.z; o[2] = (bf16)(v2 > 0.f ? v2 : 0.1f * v2);
        float v3 = acc[s][3] + bv.w; o[3] = (bf16)(v3 > 0.f ? v3 : 0.1f * v3);
        *(bf16x4*)(out + m * 128 + p) = o;
    }
}

// ---------------- V[b][y][n=(i*128+k)] = sum_j yp[b,y,j]*W3[n,j] + w3bias[n] ----------------
// Grid (16,129): b = blockIdx.x -> blocks sharing one w3b slice are dispatch-adjacent.
__global__ __launch_bounds__(256, 4) void k_vgemm(
    const bf16* __restrict__ yp,     // [16][128][128]
    const bf16* __restrict__ w3b,    // [16512][136]
    const float* __restrict__ w3bias,// [16512]
    bf16* __restrict__ V)            // [16][128][16512]
{
    __shared__ bf16 Vt[128 * 136];   // [y][n_local], ld=136
    const int b = blockIdx.x;
    const int n0 = blockIdx.y * 128;
    const int tid = threadIdx.x;
    const int wv = tid >> 6, lane = tid & 63, quad = lane >> 4, lr = lane & 15;
    const int y0 = wv * 32;

    const bf16* Ab = yp + b * 16384;

    f32x4 acc[8][2];
#pragma unroll
    for (int nt = 0; nt < 8; nt++) { acc[nt][0] = zero4(); acc[nt][1] = zero4(); }

#pragma unroll
    for (int kw = 0; kw < 4; kw++) {
        bf16x8 b0 = *(const bf16x8*)(Ab + (y0 + lr) * 128 + kw * 32 + quad * 8);
        bf16x8 b1 = *(const bf16x8*)(Ab + (y0 + 16 + lr) * 128 + kw * 32 + quad * 8);
#pragma unroll
        for (int nt = 0; nt < 8; nt++) {
            bf16x8 af = *(const bf16x8*)(w3b + (n0 + nt * 16 + lr) * 136 + kw * 32 + quad * 8);
            acc[nt][0] = MFMA(af, b0, acc[nt][0]);
            acc[nt][1] = MFMA(af, b1, acc[nt][1]);
        }
    }
#pragma unroll
    for (int nt = 0; nt < 8; nt++) {
        int nl = nt * 16 + quad * 4;
        float4 bv = *(const float4*)(w3bias + n0 + nl);
#pragma unroll
        for (int s = 0; s < 2; s++) {
            int y = y0 + s * 16 + lr;
            bf16x4 o;
            o[0] = (bf16)(acc[nt][s][0] + bv.x);
            o[1] = (bf16)(acc[nt][s][1] + bv.y);
            o[2] = (bf16)(acc[nt][s][2] + bv.z);
            o[3] = (bf16)(acc[nt][s][3] + bv.w);
            *(bf16x4*)(&Vt[y * 136 + nl]) = o;
        }
    }
    __syncthreads();
    const int yr = tid >> 4, nn = (tid & 15) * 8;
#pragma unroll
    for (int pass = 0; pass < 8; pass++) {
        int y = pass * 16 + yr;
        bf16x8 v = *(const bf16x8*)(&Vt[y * 136 + nn]);
        *(bf16x8*)(V + (b * 128 + y) * 16512 + n0 + nn) = v;
    }
}

// ---------------- k_score v4: 2D wave split, 4 waves, 4 B-sets per wave ----------------
// Wave (ih = wv&1, ch = wv>>1):
//   G1: A-rows (V tile, i)  = [ih*64, ih*64+64)  (ih0 also handles the bias row 128)
//       B-cols (zp, z)      = [ch*64, ch*64+64)  (4 sets of 16)
//   G2: A-rows (H tile, z)  = [ih*64, ih*64+64)
//       B-cols (xp, x)      = [ch*64, ch*64+64)
// Each A-fragment is now read by 2 waves (not 4) and reused over 4 MFMAs (not 2):
// ds_read_b128 per block-iter drops 264 -> ~136 (G1) and 128 -> 64 (G2).
// bz/bxf reloaded per-iteration (L1-hot 16KB tiles) to keep peak VGPR ~190.
// setprio(1) wraps the MFMA clusters (T5: phase-split + role-diverse waves).
__global__ __launch_bounds__(256, 2) void k_score(
    const bf16* __restrict__ xp,    // [16][128][128]
    const bf16* __restrict__ zp,    // [16][128][128]
    const bf16* __restrict__ V,     // [16][128][16512]
    float* __restrict__ out)        // [16][128][128][128]  (b,x,y,z)
{
    __shared__ __align__(16) bf16 Vl[2][129 * 136];  // V tile [i][k] / H tile [z][i]
    __shared__ float Hb[128];                        // H[z][128]
    const int tid = threadIdx.x;
    const int wv = tid >> 6, lane = tid & 63, quad = lane >> 4, lr = lane & 15;
    const int ih = wv & 1;                           // A-row half (i in G1, z in G2)
    const int ch = wv >> 1;                          // B-col half (z in G1, x in G2)

    const int it0 = blockIdx.x * 4;
    const int b = it0 >> 7;                          // constant for all 4 iterations
    const int y0 = it0 & 127;                        // y = y0 + n

    const bf16* Zb = zp + b * 16384;
    const bf16* Xb = xp + b * 16384;
    const bf16* Vbase = V + (b * 128 + y0) * 16512;

    // prelude: issue iteration-0 V loads (8 x 16B per thread)
    bf16x8 st[8], st4;
#pragma unroll
    for (int q = 0; q < 8; q++) st4[q] = (bf16)0.f;
#pragma unroll
    for (int u = 0; u < 8; u++) st[u] = *(const bf16x8*)(Vbase + (tid + u * 256) * 8);
    if (tid < 16) st4 = *(const bf16x8*)(Vbase + (2048 + tid) * 8);

#pragma unroll 1
    for (int n = 0; n < 4; n++) {
        bf16* Bc = &Vl[n & 1][0];      // this iteration's V tile, then H tile

        // stage this iteration's V (loads issued last iteration / prelude)
#pragma unroll
        for (int u = 0; u < 8; u++) {
            int c = tid + u * 256;
            *(bf16x8*)(Bc + (c >> 4) * 136 + (c & 15) * 8) = st[u];
        }
        if (tid < 16) *(bf16x8*)(Bc + 128 * 136 + tid * 8) = st4;

        // per-iteration zp fragments (L1-hot after iter 0; latency covered by barrier)
        bf16x8 bz[4][4];
#pragma unroll
        for (int kw = 0; kw < 4; kw++)
#pragma unroll
            for (int s = 0; s < 4; s++)
                bz[kw][s] = *(const bf16x8*)(Zb + (ch * 64 + s * 16 + lr) * 128 + kw * 32 + quad * 8);

        soft_barrier();   // V tile visible

        // ---- GEMM1: D[row=i][col=z]; wave: i in [ih*64,+64) (+bias for ih0), z in [ch*64,+64) ----
        f32x4 acc1[5][4];
#pragma unroll
        for (int it = 0; it < 5; it++)
#pragma unroll
            for (int s = 0; s < 4; s++) acc1[it][s] = zero4();

        __builtin_amdgcn_s_setprio(1);
#pragma unroll
        for (int kw = 0; kw < 4; kw++) {
#pragma unroll
            for (int it = 0; it < 4; it++) {
                bf16x8 af = *(const bf16x8*)(Bc + (ih * 64 + it * 16 + lr) * 136 + kw * 32 + quad * 8);
#pragma unroll
                for (int s = 0; s < 4; s++) acc1[it][s] = MFMA(af, bz[kw][s], acc1[it][s]);
            }
            if (ih == 0) {   // bias row i=128 (wave-uniform branch)
                bf16x8 a8;
#pragma unroll
                for (int q = 0; q < 8; q++) a8[q] = (bf16)0.f;
                if (lr == 0) a8 = *(const bf16x8*)(Bc + 128 * 136 + kw * 32 + quad * 8);
#pragma unroll
                for (int s = 0; s < 4; s++) acc1[4][s] = MFMA(a8, bz[kw][s], acc1[4][s]);
            }
        }
        __builtin_amdgcn_s_setprio(0);
        soft_barrier();   // all V reads done; region reusable for H

        // per-iteration xp fragments (consumed in G2; latency covered by H-write + barrier)
        bf16x8 bxf[4][4];
#pragma unroll
        for (int iw = 0; iw < 4; iw++)
#pragma unroll
            for (int s = 0; s < 4; s++)
                bxf[iw][s] = *(const bf16x8*)(Xb + (ch * 64 + s * 16 + lr) * 128 + iw * 32 + quad * 8);

        // H -> LDS: z = ch*64 + s*16 + lr, i = ih*64 + it*16 + quad*4
#pragma unroll
        for (int it = 0; it < 4; it++) {
#pragma unroll
            for (int s = 0; s < 4; s++) {
                bf16x4 o;
                o[0] = (bf16)acc1[it][s][0];
                o[1] = (bf16)acc1[it][s][1];
                o[2] = (bf16)acc1[it][s][2];
                o[3] = (bf16)acc1[it][s][3];
                *(bf16x4*)(Bc + (ch * 64 + s * 16 + lr) * 136 + ih * 64 + it * 16 + quad * 4) = o;
            }
        }
        if (ih == 0 && quad == 0) {
#pragma unroll
            for (int s = 0; s < 4; s++) Hb[ch * 64 + s * 16 + lr] = acc1[4][s][0];
        }
        soft_barrier();   // H tile visible

        // prefetch next V row (before the epilogue stores)
        if (n < 3) {
            const bf16* Vnx = Vbase + (n + 1) * 16512;
#pragma unroll
            for (int u = 0; u < 8; u++) st[u] = *(const bf16x8*)(Vnx + (tid + u * 256) * 8);
            if (tid < 16) st4 = *(const bf16x8*)(Vnx + (2048 + tid) * 8);
        }

        // ---- GEMM2: D[row=z][col=x]; wave: z in [ih*64,+64), x in [ch*64,+64) ----
        f32x4 acc2[4][4];
#pragma unroll
        for (int zt = 0; zt < 4; zt++)
#pragma unroll
            for (int s = 0; s < 4; s++) acc2[zt][s] = zero4();

        __builtin_amdgcn_s_setprio(1);
#pragma unroll
        for (int iw = 0; iw < 4; iw++) {
#pragma unroll
            for (int zt = 0; zt < 4; zt++) {
                bf16x8 ah = *(const bf16x8*)(Bc + (ih * 64 + zt * 16 + lr) * 136 + iw * 32 + quad * 8);
#pragma unroll
                for (int s = 0; s < 4; s++) acc2[zt][s] = MFMA(ah, bxf[iw][s], acc2[zt][s]);
            }
        }
        __builtin_amdgcn_s_setprio(0);

        // epilogue: x = ch*64 + s*16 + lr; z-chunk = ih*64 + zt*16 + quad*4
#pragma unroll
        for (int zt = 0; zt < 4; zt++) {
            int zb = ih * 64 + zt * 16 + quad * 4;
            f32x4 hb = *(const f32x4*)(&Hb[zb]);
#pragma unroll
            for (int s = 0; s < 4; s++) {
                int xx = ch * 64 + s * 16 + lr;
                f32x4 o;
                o[0] = acc2[zt][s][0] + hb[0];
                o[1] = acc2[zt][s][1] + hb[1];
                o[2] = acc2[zt][s][2] + hb[2];
                o[3] = acc2[zt][s][3] + hb[3];
                *(f32x4*)(out + (((b * 128 + xx) * 128 + (y0 + n)) * 128 + zb)) = o;
            }
        }
    }
}

extern "C" void kernel_launch(void* const* d_in, const int* in_sizes, int n_in,
                              void* d_out, int out_size, void* d_ws, size_t ws_size,
                              hipStream_t stream) {
    const float* x   = (const float*)d_in[0];
    const float* xsp = (const float*)d_in[1];
    const float* Wx  = (const float*)d_in[2];
    const float* bx  = (const float*)d_in[3];
    const float* Wy  = (const float*)d_in[4];
    const float* by  = (const float*)d_in[5];
    const float* Wz  = (const float*)d_in[6];
    const float* bz  = (const float*)d_in[7];
    const float* W3  = (const float*)d_in[8];
    float* out = (float*)d_out;

    char* ws = (char*)d_ws;
    bf16*  wbf    = (bf16*)(ws + 8388608);         // 768 KiB
    bf16*  w3b    = (bf16*)(ws + 9175040);         // 16512*136*2 = 4.28 MiB
    bf16*  pout   = (bf16*)(ws + 13666304);        // 3*2048*128*2 = 1.5 MiB (xp,yp,zp)
    bf16*  V      = (bf16*)(ws + 15239168);        // 16*128*16512*2 = 64.5 MiB
    float* w3bias = (float*)(ws + 82872320);       // 66 KB

    k_prep<<<2160, 256, 0, stream>>>(Wx, Wy, Wz, W3, wbf, w3b, w3bias);
    k_mlp<<<dim3(128, 3), 256, 0, stream>>>(xsp, x, wbf, bx, by, bz, pout);
    k_vgemm<<<dim3(16, 129), 256, 0, stream>>>(pout + 262144 /*yp*/, w3b, w3bias, V);
    k_score<<<512, 256, 0, stream>>>(pout /*xp*/, pout + 524288 /*zp*/, V, out);
}

// Round 8
// 241.761 us; speedup vs baseline: 1.1468x; 1.1468x over previous
//
#include <hip/hip_runtime.h>

typedef __bf16 bf16;
typedef __bf16 bf16x8 __attribute__((ext_vector_type(8)));
typedef __bf16 bf16x4 __attribute__((ext_vector_type(4)));
typedef float f32x4 __attribute__((ext_vector_type(4)));

#define MFMA(a, b, c) __builtin_amdgcn_mfma_f32_16x16x32_bf16((a), (b), (c), 0, 0, 0)

static __device__ __forceinline__ f32x4 zero4() {
    f32x4 z; z[0] = 0.f; z[1] = 0.f; z[2] = 0.f; z[3] = 0.f; return z;
}

// LDS-only barrier: all cross-wave deps at these barriers are LDS-carried;
// leaves global loads/stores in flight, unlike __syncthreads().
static __device__ __forceinline__ void soft_barrier() {
    __builtin_amdgcn_sched_barrier(0);
    asm volatile("s_waitcnt lgkmcnt(0)" ::: "memory");
    __builtin_amdgcn_s_barrier();
    __builtin_amdgcn_sched_barrier(0);
}

// ---------------- prep: W (bf16) + W3 (bf16, padded) conversions ----------------
__global__ __launch_bounds__(256) void k_prep(
    const float* __restrict__ Wx, const float* __restrict__ Wy, const float* __restrict__ Wz,
    const float* __restrict__ W3,
    bf16* __restrict__ wbf, bf16* __restrict__ w3b, float* __restrict__ w3bias)
{
    const int b = blockIdx.x, t = threadIdx.x;
    if (b < 96) {
        int proj = b >> 5;
        const float* src = (proj == 0) ? Wx : (proj == 1) ? Wy : Wz;
        bf16* dst = wbf + proj * 131072;
        int o = (b & 31) * 4096 + t * 16;
#pragma unroll
        for (int u = 0; u < 4; u++) {
            float4 v = *(const float4*)(src + o + u * 4);
            bf16x4 w; w[0] = (bf16)v.x; w[1] = (bf16)v.y; w[2] = (bf16)v.z; w[3] = (bf16)v.w;
            *(bf16x4*)(dst + o + u * 4) = w;
        }
    } else {
        int nb = b - 96;                     // 0..2063
        int n = nb * 8 + (t >> 5);           // row of W3 (i*128+k), < 16512
        int c = t & 31;
        const float* row = W3 + n * 129;
        float v0 = row[4 * c + 0];
        float v1 = row[4 * c + 1];
        float v2 = row[4 * c + 2];
        float v3 = row[4 * c + 3];
        bf16x4 w;
        w[0] = (bf16)v0; w[1] = (bf16)v1; w[2] = (bf16)v2; w[3] = (bf16)v3;
        *(bf16x4*)(w3b + n * 136 + 4 * c) = w;
        if (c == 0) w3bias[n] = row[128];
    }
}

// ---------------- MLP: pout[proj][m][p] = leaky_relu(A @ W^T + b) ----------------
__global__ __launch_bounds__(256) void k_mlp(
    const float* __restrict__ xsp, const float* __restrict__ x,
    const bf16* __restrict__ wbf,
    const float* __restrict__ bx, const float* __restrict__ by, const float* __restrict__ bz,
    bf16* __restrict__ pout)
{
    __shared__ bf16 Al[16 * 1032];
    const int proj = blockIdx.y;
    const float* A = (proj == 2) ? x : xsp;
    const bf16* W = wbf + proj * 131072;
    const float* bias = (proj == 0) ? bx : (proj == 1) ? by : bz;
    bf16* out = pout + proj * 262144;

    const int tid = threadIdx.x;
    const int wv = tid >> 6, lane = tid & 63, quad = lane >> 4, lr = lane & 15;
    const int m0 = blockIdx.x * 16;

    {
        const float* Asrc = A + m0 * 1024;
        const int rr = tid >> 7, cc = (tid & 127) * 8;
#pragma unroll
        for (int i = 0; i < 8; i++) {
            int r = i * 2 + rr;
            float4 v0 = *(const float4*)(Asrc + r * 1024 + cc);
            float4 v1 = *(const float4*)(Asrc + r * 1024 + cc + 4);
            bf16x8 w;
            w[0] = (bf16)v0.x; w[1] = (bf16)v0.y; w[2] = (bf16)v0.z; w[3] = (bf16)v0.w;
            w[4] = (bf16)v1.x; w[5] = (bf16)v1.y; w[6] = (bf16)v1.z; w[7] = (bf16)v1.w;
            *(bf16x8*)(&Al[r * 1032 + cc]) = w;
        }
    }
    __syncthreads();

    f32x4 acc[2];
    acc[0] = zero4(); acc[1] = zero4();

    const bf16* brow = Al + lr * 1032 + quad * 8;
    const bf16* arow = W + (wv * 16 + lr) * 1024 + quad * 8;

#pragma unroll 4
    for (int kw = 0; kw < 32; kw++) {
        bf16x8 bfr = *(const bf16x8*)(brow + kw * 32);
        bf16x8 a0 = *(const bf16x8*)(arow + kw * 32);
        bf16x8 a1 = *(const bf16x8*)(arow + 65536 + kw * 32);
        acc[0] = MFMA(a0, bfr, acc[0]);
        acc[1] = MFMA(a1, bfr, acc[1]);
    }
#pragma unroll
    for (int s = 0; s < 2; s++) {
        int p = (wv + s * 4) * 16 + quad * 4;
        float4 bv = *(const float4*)(bias + p);
        int m = m0 + lr;
        bf16x4 o;
        float v0 = acc[s][0] + bv.x; o[0] = (bf16)(v0 > 0.f ? v0 : 0.1f * v0);
        float v1 = acc[s][1] + bv.y; o[1] = (bf16)(v1 > 0.f ? v1 : 0.1f * v1);
        float v2 = acc[s][2] + bv.z; o[2] = (bf16)(v2 > 0.f ? v2 : 0.1f * v2);
        float v3 = acc[s][3] + bv.w; o[3] = (bf16)(v3 > 0.f ? v3 : 0.1f * v3);
        *(bf16x4*)(out + m * 128 + p) = o;
    }
}

// ---------------- V[b][y][n=(i*128+k)] = sum_j yp[b,y,j]*W3[n,j] + w3bias[n] ----------------
// Grid (16,129): b = blockIdx.x -> the 16 blocks sharing one w3b slice are
// dispatch-adjacent (L2/L3-hot) instead of 129 apart (16x HBM refetch).
__global__ __launch_bounds__(256, 4) void k_vgemm(
    const bf16* __restrict__ yp,     // [16][128][128]
    const bf16* __restrict__ w3b,    // [16512][136]
    const float* __restrict__ w3bias,// [16512]
    bf16* __restrict__ V)            // [16][128][16512]
{
    __shared__ bf16 Vt[128 * 136];   // [y][n_local], ld=136
    const int b = blockIdx.x;
    const int n0 = blockIdx.y * 128;
    const int tid = threadIdx.x;
    const int wv = tid >> 6, lane = tid & 63, quad = lane >> 4, lr = lane & 15;
    const int y0 = wv * 32;

    const bf16* Ab = yp + b * 16384;

    f32x4 acc[8][2];
#pragma unroll
    for (int nt = 0; nt < 8; nt++) { acc[nt][0] = zero4(); acc[nt][1] = zero4(); }

#pragma unroll
    for (int kw = 0; kw < 4; kw++) {
        bf16x8 b0 = *(const bf16x8*)(Ab + (y0 + lr) * 128 + kw * 32 + quad * 8);
        bf16x8 b1 = *(const bf16x8*)(Ab + (y0 + 16 + lr) * 128 + kw * 32 + quad * 8);
#pragma unroll
        for (int nt = 0; nt < 8; nt++) {
            bf16x8 af = *(const bf16x8*)(w3b + (n0 + nt * 16 + lr) * 136 + kw * 32 + quad * 8);
            acc[nt][0] = MFMA(af, b0, acc[nt][0]);
            acc[nt][1] = MFMA(af, b1, acc[nt][1]);
        }
    }
#pragma unroll
    for (int nt = 0; nt < 8; nt++) {
        int nl = nt * 16 + quad * 4;
        float4 bv = *(const float4*)(w3bias + n0 + nl);
#pragma unroll
        for (int s = 0; s < 2; s++) {
            int y = y0 + s * 16 + lr;
            bf16x4 o;
            o[0] = (bf16)(acc[nt][s][0] + bv.x);
            o[1] = (bf16)(acc[nt][s][1] + bv.y);
            o[2] = (bf16)(acc[nt][s][2] + bv.z);
            o[3] = (bf16)(acc[nt][s][3] + bv.w);
            *(bf16x4*)(&Vt[y * 136 + nl]) = o;
        }
    }
    __syncthreads();
    const int yr = tid >> 4, nn = (tid & 15) * 8;
#pragma unroll
    for (int pass = 0; pass < 8; pass++) {
        int y = pass * 16 + yr;
        bf16x8 v = *(const bf16x8*)(&Vt[y * 136 + nn]);
        *(bf16x8*)(V + (b * 128 + y) * 16512 + n0 + nn) = v;
    }
}

// ---------------- k_score v3 (verified best, round 6): 256 threads / 4 waves ----------------
// Each wave owns 32 output cols (2 B-sets); A-fragments read once per 2 MFMAs.
// Loop-invariant zp/xp fragments; soft barriers keep stores/prefetch in flight.
// v4 (2D wave-split + per-iteration fragment reloads) REGRESSED: the per-iter
// VMEM reloads put L2 latency on the critical path between barriers. Reverted.
__global__ __launch_bounds__(256, 2) void k_score(
    const bf16* __restrict__ xp,    // [16][128][128]
    const bf16* __restrict__ zp,    // [16][128][128]
    const bf16* __restrict__ V,     // [16][128][16512]
    float* __restrict__ out)        // [16][128][128][128]  (b,x,y,z)
{
    __shared__ __align__(16) bf16 Vl[2][129 * 136];  // V tile [i][k] / H tile [z][i]
    __shared__ float Hb[128];                        // H[z][128]
    const int tid = threadIdx.x;
    const int wv = tid >> 6, lane = tid & 63, quad = lane >> 4, lr = lane & 15;
    const int c0 = wv * 32;                          // wave column base (z in G1, x in G2)

    const int it0 = blockIdx.x * 4;
    const int b = it0 >> 7;                          // constant for all 4 iterations
    const int y0 = it0 & 127;                        // y = y0 + n

    const bf16* Zb = zp + b * 16384;
    const bf16* Xb = xp + b * 16384;
    const bf16* Vbase = V + (b * 128 + y0) * 16512;

    // prelude: issue iteration-0 V loads (8 x 16B per thread), then fragments
    bf16x8 st[8], st4;
#pragma unroll
    for (int q = 0; q < 8; q++) st4[q] = (bf16)0.f;
#pragma unroll
    for (int u = 0; u < 8; u++) st[u] = *(const bf16x8*)(Vbase + (tid + u * 256) * 8);
    if (tid < 16) st4 = *(const bf16x8*)(Vbase + (2048 + tid) * 8);

    // loop-invariant zp/xp fragments: wave owns cols c0..c0+31 (two 16-col sets)
    bf16x8 bz[4][2], bxf[4][2];
#pragma unroll
    for (int kw = 0; kw < 4; kw++)
#pragma unroll
        for (int s = 0; s < 2; s++)
            bz[kw][s] = *(const bf16x8*)(Zb + (c0 + s * 16 + lr) * 128 + kw * 32 + quad * 8);
#pragma unroll
    for (int iw = 0; iw < 4; iw++)
#pragma unroll
        for (int s = 0; s < 2; s++)
            bxf[iw][s] = *(const bf16x8*)(Xb + (c0 + s * 16 + lr) * 128 + iw * 32 + quad * 8);

#pragma unroll 1
    for (int n = 0; n < 4; n++) {
        bf16* Bc = &Vl[n & 1][0];      // this iteration's V tile, then H tile

        // stage this iteration's V (loads issued last iteration / prelude)
#pragma unroll
        for (int u = 0; u < 8; u++) {
            int c = tid + u * 256;
            *(bf16x8*)(Bc + (c >> 4) * 136 + (c & 15) * 8) = st[u];
        }
        if (tid < 16) *(bf16x8*)(Bc + 128 * 136 + tid * 8) = st4;
        soft_barrier();   // V tile visible

        // ---- GEMM1: D[row=i][col=z], wave owns z in [c0, c0+32) ----
        f32x4 acc1[9][2];
#pragma unroll
        for (int it = 0; it < 9; it++) { acc1[it][0] = zero4(); acc1[it][1] = zero4(); }

#pragma unroll
        for (int kw = 0; kw < 4; kw++) {
#pragma unroll
            for (int it = 0; it < 8; it++) {
                bf16x8 af = *(const bf16x8*)(Bc + (it * 16 + lr) * 136 + kw * 32 + quad * 8);
                acc1[it][0] = MFMA(af, bz[kw][0], acc1[it][0]);
                acc1[it][1] = MFMA(af, bz[kw][1], acc1[it][1]);
            }
            bf16x8 a8;
#pragma unroll
            for (int q = 0; q < 8; q++) a8[q] = (bf16)0.f;
            if (lr == 0) a8 = *(const bf16x8*)(Bc + 128 * 136 + kw * 32 + quad * 8);
            acc1[8][0] = MFMA(a8, bz[kw][0], acc1[8][0]);
            acc1[8][1] = MFMA(a8, bz[kw][1], acc1[8][1]);
        }
        soft_barrier();   // all V reads done; region reusable for H

        // H -> LDS: thread writes TWO z-rows (c0+lr, c0+16+lr)
#pragma unroll
        for (int it = 0; it < 8; it++) {
            int i = it * 16 + quad * 4;
#pragma unroll
            for (int s = 0; s < 2; s++) {
                bf16x4 o;
                o[0] = (bf16)acc1[it][s][0];
                o[1] = (bf16)acc1[it][s][1];
                o[2] = (bf16)acc1[it][s][2];
                o[3] = (bf16)acc1[it][s][3];
                *(bf16x4*)(Bc + (c0 + s * 16 + lr) * 136 + i) = o;
            }
        }
        if (quad == 0) {
            Hb[c0 + lr]      = acc1[8][0][0];   // bias (i=128) lives in D row 0
            Hb[c0 + 16 + lr] = acc1[8][1][0];
        }
        soft_barrier();   // H tile visible

        // prefetch next V row (before the epilogue stores)
        if (n < 3) {
            const bf16* Vnx = Vbase + (n + 1) * 16512;
#pragma unroll
            for (int u = 0; u < 8; u++) st[u] = *(const bf16x8*)(Vnx + (tid + u * 256) * 8);
            if (tid < 16) st4 = *(const bf16x8*)(Vnx + (2048 + tid) * 8);
        }

        // ---- GEMM2: D[row=z][col=x], wave owns x in [c0, c0+32) ----
        f32x4 acc2[8][2];
#pragma unroll
        for (int zt = 0; zt < 8; zt++) { acc2[zt][0] = zero4(); acc2[zt][1] = zero4(); }

#pragma unroll
        for (int iw = 0; iw < 4; iw++) {
#pragma unroll
            for (int zt = 0; zt < 8; zt++) {
                bf16x8 ah = *(const bf16x8*)(Bc + (zt * 16 + lr) * 136 + iw * 32 + quad * 8);
                acc2[zt][0] = MFMA(ah, bxf[iw][0], acc2[zt][0]);
                acc2[zt][1] = MFMA(ah, bxf[iw][1], acc2[zt][1]);
            }
        }
        // epilogue: x = c0 + s*16 + lr, z = zt*16 + quad*4
#pragma unroll
        for (int zt = 0; zt < 8; zt++) {
            int zb = zt * 16 + quad * 4;
            f32x4 hb = *(const f32x4*)(&Hb[zb]);
#pragma unroll
            for (int s = 0; s < 2; s++) {
                int xx = c0 + s * 16 + lr;
                f32x4 o;
                o[0] = acc2[zt][s][0] + hb[0];
                o[1] = acc2[zt][s][1] + hb[1];
                o[2] = acc2[zt][s][2] + hb[2];
                o[3] = acc2[zt][s][3] + hb[3];
                *(f32x4*)(out + (((b * 128 + xx) * 128 + (y0 + n)) * 128 + zb)) = o;
            }
        }
    }
}

extern "C" void kernel_launch(void* const* d_in, const int* in_sizes, int n_in,
                              void* d_out, int out_size, void* d_ws, size_t ws_size,
                              hipStream_t stream) {
    const float* x   = (const float*)d_in[0];
    const float* xsp = (const float*)d_in[1];
    const float* Wx  = (const float*)d_in[2];
    const float* bx  = (const float*)d_in[3];
    const float* Wy  = (const float*)d_in[4];
    const float* by  = (const float*)d_in[5];
    const float* Wz  = (const float*)d_in[6];
    const float* bz  = (const float*)d_in[7];
    const float* W3  = (const float*)d_in[8];
    float* out = (float*)d_out;

    char* ws = (char*)d_ws;
    bf16*  wbf    = (bf16*)(ws + 8388608);         // 768 KiB
    bf16*  w3b    = (bf16*)(ws + 9175040);         // 16512*136*2 = 4.28 MiB
    bf16*  pout   = (bf16*)(ws + 13666304);        // 3*2048*128*2 = 1.5 MiB (xp,yp,zp)
    bf16*  V      = (bf16*)(ws + 15239168);        // 16*128*16512*2 = 64.5 MiB
    float* w3bias = (float*)(ws + 82872320);       // 66 KB

    k_prep<<<2160, 256, 0, stream>>>(Wx, Wy, Wz, W3, wbf, w3b, w3bias);
    k_mlp<<<dim3(128, 3), 256, 0, stream>>>(xsp, x, wbf, bx, by, bz, pout);
    k_vgemm<<<dim3(16, 129), 256, 0, stream>>>(pout + 262144 /*yp*/, w3b, w3bias, V);
    k_score<<<512, 256, 0, stream>>>(pout /*xp*/, pout + 524288 /*zp*/, V, out);
}